// Round 1
// baseline (805.079 us; speedup 1.0000x reference)
//
#include <hip/hip_runtime.h>
#include <stdint.h>

// Problem constants
#define B_ROWS   10240
#define IN_DIM   4096
#define OUT_DIM  4096
#define K_CL     10
#define CL_ROWS  1024      // B_ROWS / K_CL
#define QMAXF    255.0f

typedef __attribute__((ext_vector_type(8))) short short8;
typedef __attribute__((ext_vector_type(4))) float f32x4;

// ---------- helpers ----------
__device__ inline float devinf() { return __int_as_float(0x7f800000); }

__device__ inline void atomicMinF(float* addr, float v) {
    if (v >= 0.f) atomicMin((int*)addr, __float_as_int(v));
    else          atomicMax((unsigned int*)addr, __float_as_uint(v));
}
__device__ inline void atomicMaxF(float* addr, float v) {
    if (v >= 0.f) atomicMax((int*)addr, __float_as_int(v));
    else          atomicMin((unsigned int*)addr, __float_as_uint(v));
}

// fp32 -> bf16 round-to-nearest-even
__device__ inline unsigned short f2bf(float f) {
    unsigned int u = __float_as_uint(f);
    u += 0x7fffu + ((u >> 16) & 1u);
    return (unsigned short)(u >> 16);
}

// async global->LDS, 16B per lane (global_load_lds_dwordx4)
__device__ inline void gload16(const unsigned short* g, unsigned short* l) {
    __builtin_amdgcn_global_load_lds(
        (const __attribute__((address_space(1))) unsigned int*)g,
        (__attribute__((address_space(3))) unsigned int*)l,
        16, 0, 0);
}

// ---------- ws layout (floats at base) ----------
// [0]=wmin [1]=wmax [2..11]=cluster min [12..21]=cluster max
// [22..31]=s3 [32..41]=z3
// byte 256: x_bf16 (10240*4096*2)   then w_bf16 (4096*4096*2)

// ---------- kernels ----------
__global__ void k_init(float* st) {
    int t = threadIdx.x;
    if (t == 0) { st[0] = devinf(); st[1] = -devinf(); }
    if (t >= 2 && t < 12)  st[t] = devinf();     // cluster mins
    if (t >= 12 && t < 22) st[t] = -devinf();    // cluster maxs
}

__global__ void k_wminmax(const float4* __restrict__ w, int n4, float* st) {
    float mn = devinf(), mx = -devinf();
    for (int i = blockIdx.x * blockDim.x + threadIdx.x; i < n4;
         i += gridDim.x * blockDim.x) {
        float4 v = w[i];
        mn = fminf(mn, fminf(fminf(v.x, v.y), fminf(v.z, v.w)));
        mx = fmaxf(mx, fmaxf(fmaxf(v.x, v.y), fmaxf(v.z, v.w)));
    }
    for (int o = 32; o; o >>= 1) {
        mn = fminf(mn, __shfl_down(mn, o));
        mx = fmaxf(mx, __shfl_down(mx, o));
    }
    __shared__ float smn[4], smx[4];
    int lane = threadIdx.x & 63, wv = threadIdx.x >> 6;
    if (lane == 0) { smn[wv] = mn; smx[wv] = mx; }
    __syncthreads();
    if (threadIdx.x == 0) {
        for (int i = 1; i < 4; ++i) { mn = fminf(mn, smn[i]); mx = fmaxf(mx, smx[i]); }
        atomicMinF(&st[0], mn);
        atomicMaxF(&st[1], mx);
    }
}

// fake-quantize weight (global qparams) and cast to bf16
__global__ void k_wquant(const float4* __restrict__ w, ushort4* __restrict__ o,
                         int n4, const float* st) {
    float mn = st[0], mx = st[1];
    float s = (mx - mn) / QMAXF;
    float z = -rintf(mn / s);
    for (int i = blockIdx.x * blockDim.x + threadIdx.x; i < n4;
         i += gridDim.x * blockDim.x) {
        float4 v = w[i];
        float qx = (fminf(fmaxf(rintf(v.x / s + z), 0.f), QMAXF) - z) * s;
        float qy = (fminf(fmaxf(rintf(v.y / s + z), 0.f), QMAXF) - z) * s;
        float qz = (fminf(fmaxf(rintf(v.z / s + z), 0.f), QMAXF) - z) * s;
        float qw = (fminf(fmaxf(rintf(v.w / s + z), 0.f), QMAXF) - z) * s;
        ushort4 r; r.x = f2bf(qx); r.y = f2bf(qy); r.z = f2bf(qz); r.w = f2bf(qw);
        o[i] = r;
    }
}

__global__ void k_xcast(const float4* __restrict__ x, ushort4* __restrict__ o, int n4) {
    for (int i = blockIdx.x * blockDim.x + threadIdx.x; i < n4;
         i += gridDim.x * blockDim.x) {
        float4 v = x[i];
        ushort4 r; r.x = f2bf(v.x); r.y = f2bf(v.y); r.z = f2bf(v.z); r.w = f2bf(v.w);
        o[i] = r;
    }
}

// m97-style bf16 NT GEMM: C[M=10240][N=4096] = A[M][K] * Bw[N][K]^T + bias
// 128x128 tile, BK=32, 4 waves in 2x2, 4x4 16x16x32 MFMA per wave.
// Fused: bias add, fp32 store to C, per-cluster min/max atomics.
__global__ __launch_bounds__(256) void k_gemm(
    const unsigned short* __restrict__ A, const unsigned short* __restrict__ Bw,
    const float* __restrict__ bias, float* __restrict__ C,
    float* clmin, float* clmax)
{
    const int K = IN_DIM;
    __shared__ __align__(16) unsigned short As[128 * 32];
    __shared__ __align__(16) unsigned short Bs[128 * 32];
    __shared__ float red[8];

    int tid = threadIdx.x;
    int wv = tid >> 6, lane = tid & 63;
    int wr = wv >> 1, wc = wv & 1;          // wave 2x2 position
    int m16 = lane & 15, quad = lane >> 4;  // MFMA lane decomposition
    int bM = blockIdx.y, bN = blockIdx.x;

    // staging: each wave instruction covers 16 rows x 32 cols (64 lanes * 8 bf16)
    int srow = wv * 16 + (lane >> 2);       // row within tile for r=0
    int scol = (lane & 3) * 8;
    const unsigned short* gA = A + (size_t)(bM * 128 + srow) * K + scol;
    const unsigned short* gB = Bw + (size_t)(bN * 128 + srow) * K + scol;
    unsigned short* lA = As + srow * 32 + scol;
    unsigned short* lB = Bs + srow * 32 + scol;

    f32x4 acc[4][4] = {};

    for (int k0 = 0; k0 < K; k0 += 32) {
        gload16(gA + k0, lA);
        gload16(gA + k0 + (size_t)64 * K, lA + 64 * 32);
        gload16(gB + k0, lB);
        gload16(gB + k0 + (size_t)64 * K, lB + 64 * 32);
        __syncthreads();

        short8 af[4], bfr[4];
#pragma unroll
        for (int i = 0; i < 4; ++i) {
            af[i]  = *(const short8*)(As + (wr * 64 + i * 16 + m16) * 32 + quad * 8);
            bfr[i] = *(const short8*)(Bs + (wc * 64 + i * 16 + m16) * 32 + quad * 8);
        }
#pragma unroll
        for (int mi = 0; mi < 4; ++mi)
#pragma unroll
            for (int ni = 0; ni < 4; ++ni)
                acc[mi][ni] = __builtin_amdgcn_mfma_f32_16x16x32_bf16(
                    af[mi], bfr[ni], acc[mi][ni], 0, 0, 0);
        __syncthreads();
    }

    // epilogue: bias add, store fp32, track min/max
    float bv[4];
#pragma unroll
    for (int ni = 0; ni < 4; ++ni)
        bv[ni] = bias[bN * 128 + wc * 64 + ni * 16 + m16];

    float mn = devinf(), mx = -devinf();
#pragma unroll
    for (int mi = 0; mi < 4; ++mi) {
        int r0 = bM * 128 + wr * 64 + mi * 16 + quad * 4;
#pragma unroll
        for (int ni = 0; ni < 4; ++ni) {
            int c = bN * 128 + wc * 64 + ni * 16 + m16;
#pragma unroll
            for (int k = 0; k < 4; ++k) {
                float v = acc[mi][ni][k] + bv[ni];
                C[(size_t)(r0 + k) * OUT_DIM + c] = v;
                mn = fminf(mn, v);
                mx = fmaxf(mx, v);
            }
        }
    }
    for (int o = 32; o; o >>= 1) {
        mn = fminf(mn, __shfl_down(mn, o));
        mx = fmaxf(mx, __shfl_down(mx, o));
    }
    if (lane == 0) { red[wv] = mn; red[4 + wv] = mx; }
    __syncthreads();
    if (tid == 0) {
        for (int i = 1; i < 4; ++i) { mn = fminf(mn, red[i]); mx = fmaxf(mx, red[4 + i]); }
        int cl = bM >> 3;  // 8 row-blocks of 128 per 1024-row cluster
        atomicMinF(&clmin[cl], mn);
        atomicMaxF(&clmax[cl], mx);
    }
}

// EMA range update + qparams; writes new_range to out tail
__global__ void k_range(const float* st, const float* __restrict__ act_range,
                        const int* __restrict__ ci, float* out_tail, float* qp) {
    int t = threadIdx.x;
    if (t < K_CL) {  // copy original act_range rows
        out_tail[2 * t]     = act_range[2 * t];
        out_tail[2 * t + 1] = act_range[2 * t + 1];
    }
    __syncthreads();
    if (t < K_CL) {
        int c = ci[2 * t];
        float omn = act_range[2 * c], omx = act_range[2 * c + 1];
        float nm = omn * 0.999f + st[2 + t] * 0.001f;
        float nx = omx * 0.999f + st[12 + t] * 0.001f;
        out_tail[2 * c]     = nm;
        out_tail[2 * c + 1] = nx;
        float s = (nx - nm) / QMAXF;
        float z = -rintf(nm / s);
        qp[t] = s;
        qp[K_CL + t] = z;
    }
}

// in-place per-cluster fake-quantize of the output
__global__ void k_qout(float4* __restrict__ out, const float* __restrict__ qp, int n4) {
    for (int i = blockIdx.x * blockDim.x + threadIdx.x; i < n4;
         i += gridDim.x * blockDim.x) {
        int cl = i >> 20;  // 1024*4096/4 = 2^20 float4 per cluster
        float s = qp[cl], z = qp[K_CL + cl];
        float4 v = out[i];
        v.x = (fminf(fmaxf(rintf(v.x / s + z), 0.f), QMAXF) - z) * s;
        v.y = (fminf(fmaxf(rintf(v.y / s + z), 0.f), QMAXF) - z) * s;
        v.z = (fminf(fmaxf(rintf(v.z / s + z), 0.f), QMAXF) - z) * s;
        v.w = (fminf(fmaxf(rintf(v.w / s + z), 0.f), QMAXF) - z) * s;
        out[i] = v;
    }
}

extern "C" void kernel_launch(void* const* d_in, const int* in_sizes, int n_in,
                              void* d_out, int out_size, void* d_ws, size_t ws_size,
                              hipStream_t stream) {
    const float* x         = (const float*)d_in[0];
    const float* w         = (const float*)d_in[1];
    const float* bias      = (const float*)d_in[2];
    const float* act_range = (const float*)d_in[3];
    const int*   ci        = (const int*)d_in[4];
    float* out = (float*)d_out;

    float* st = (float*)d_ws;
    unsigned short* x_bf = (unsigned short*)((char*)d_ws + 256);
    unsigned short* w_bf = (unsigned short*)((char*)d_ws + 256 + (size_t)B_ROWS * IN_DIM * 2);

    k_init<<<1, 64, 0, stream>>>(st);
    k_wminmax<<<512, 256, 0, stream>>>((const float4*)w, OUT_DIM * IN_DIM / 4, st);
    k_wquant<<<1024, 256, 0, stream>>>((const float4*)w, (ushort4*)w_bf,
                                       OUT_DIM * IN_DIM / 4, st);
    k_xcast<<<2048, 256, 0, stream>>>((const float4*)x, (ushort4*)x_bf,
                                      B_ROWS * IN_DIM / 4);
    dim3 grid(OUT_DIM / 128, B_ROWS / 128);
    k_gemm<<<grid, 256, 0, stream>>>(x_bf, w_bf, bias, out, st + 2, st + 12);
    k_range<<<1, 64, 0, stream>>>(st, act_range, ci,
                                  out + (size_t)B_ROWS * OUT_DIM, st + 22);
    k_qout<<<2048, 256, 0, stream>>>((float4*)out, st + 22, B_ROWS * OUT_DIM / 4);
}

// Round 2
// 633.535 us; speedup vs baseline: 1.2708x; 1.2708x over previous
//
#include <hip/hip_runtime.h>
#include <stdint.h>

// Problem constants
#define B_ROWS   10240
#define IN_DIM   4096
#define OUT_DIM  4096
#define K_CL     10
#define QMAXF    255.0f

typedef __attribute__((ext_vector_type(8)))  int   int8v;
typedef __attribute__((ext_vector_type(16))) float f32x16;

// ---------- helpers ----------
__device__ inline float devinf() { return __int_as_float(0x7f800000); }

__device__ inline void atomicMinF(float* addr, float v) {
    if (v >= 0.f) atomicMin((int*)addr, __float_as_int(v));
    else          atomicMax((unsigned int*)addr, __float_as_uint(v));
}
__device__ inline void atomicMaxF(float* addr, float v) {
    if (v >= 0.f) atomicMax((int*)addr, __float_as_int(v));
    else          atomicMin((unsigned int*)addr, __float_as_uint(v));
}

// pack 4 floats -> 4x fp8 e4m3 (OCP), RNE + saturate
__device__ inline unsigned f2fp8x4(float a, float b, float c, float d) {
    int v = 0;
    v = __builtin_amdgcn_cvt_pk_fp8_f32(a, b, v, false);  // low 16 bits
    v = __builtin_amdgcn_cvt_pk_fp8_f32(c, d, v, true);   // high 16 bits
    return (unsigned)v;
}

// async global->LDS, 16B per lane (global_load_lds_dwordx4)
__device__ inline void gload16(const unsigned char* g, unsigned char* l) {
    __builtin_amdgcn_global_load_lds(
        (const __attribute__((address_space(1))) unsigned int*)g,
        (__attribute__((address_space(3))) unsigned int*)l,
        16, 0, 0);
}

// ---------- ws layout (floats at base) ----------
// [0]=wmin [1]=wmax [2..11]=cluster min [12..21]=cluster max [22..41]=s3,z3
// byte 256: x_fp8 (10240*4096)   then w_fp8 (4096*4096)

__global__ void k_init(float* st) {
    int t = threadIdx.x;
    if (t == 0) { st[0] = devinf(); st[1] = -devinf(); }
    if (t >= 2 && t < 12)  st[t] = devinf();
    if (t >= 12 && t < 22) st[t] = -devinf();
}

__global__ void k_wminmax(const float4* __restrict__ w, int n4, float* st) {
    float mn = devinf(), mx = -devinf();
    for (int i = blockIdx.x * blockDim.x + threadIdx.x; i < n4;
         i += gridDim.x * blockDim.x) {
        float4 v = w[i];
        mn = fminf(mn, fminf(fminf(v.x, v.y), fminf(v.z, v.w)));
        mx = fmaxf(mx, fmaxf(fmaxf(v.x, v.y), fmaxf(v.z, v.w)));
    }
    for (int o = 32; o; o >>= 1) {
        mn = fminf(mn, __shfl_down(mn, o));
        mx = fmaxf(mx, __shfl_down(mx, o));
    }
    __shared__ float smn[4], smx[4];
    int lane = threadIdx.x & 63, wv = threadIdx.x >> 6;
    if (lane == 0) { smn[wv] = mn; smx[wv] = mx; }
    __syncthreads();
    if (threadIdx.x == 0) {
        for (int i = 1; i < 4; ++i) { mn = fminf(mn, smn[i]); mx = fmaxf(mx, smx[i]); }
        atomicMinF(&st[0], mn);
        atomicMaxF(&st[1], mx);
    }
}

// fake-quantize weight (global qparams) and cast to fp8 e4m3; 16 floats/thread
__global__ void k_wquant(const float4* __restrict__ w, uint4* __restrict__ o,
                         int n16, const float* st) {
    float mn = st[0], mx = st[1];
    float s = (mx - mn) / QMAXF;
    float z = -rintf(mn / s);
    for (int i = blockIdx.x * blockDim.x + threadIdx.x; i < n16;
         i += gridDim.x * blockDim.x) {
        uint4 r;
        unsigned* rp = (unsigned*)&r;
#pragma unroll
        for (int j = 0; j < 4; ++j) {
            float4 v = w[i * 4 + j];
            float qx = (fminf(fmaxf(rintf(v.x / s + z), 0.f), QMAXF) - z) * s;
            float qy = (fminf(fmaxf(rintf(v.y / s + z), 0.f), QMAXF) - z) * s;
            float qz = (fminf(fmaxf(rintf(v.z / s + z), 0.f), QMAXF) - z) * s;
            float qw = (fminf(fmaxf(rintf(v.w / s + z), 0.f), QMAXF) - z) * s;
            rp[j] = f2fp8x4(qx, qy, qz, qw);
        }
        o[i] = r;
    }
}

// cast x -> fp8 e4m3; 16 floats/thread
__global__ void k_xcast(const float4* __restrict__ x, uint4* __restrict__ o, int n16) {
    for (int i = blockIdx.x * blockDim.x + threadIdx.x; i < n16;
         i += gridDim.x * blockDim.x) {
        uint4 r;
        unsigned* rp = (unsigned*)&r;
#pragma unroll
        for (int j = 0; j < 4; ++j) {
            float4 v = x[i * 4 + j];
            rp[j] = f2fp8x4(v.x, v.y, v.z, v.w);
        }
        o[i] = r;
    }
}

// MX-fp8 NT GEMM: C[10240][4096] = A[M][K] * Bw[N][K]^T + bias (fp8 e4m3 inputs)
// 128x128 tile, BK=64 (bytes), 4 waves 2x2, each wave 2x2 of 32x32x64 scaled MFMA
// (scales pinned to 1.0 = 0x7f). Fused: bias, fp32 store, per-cluster min/max.
__global__ __launch_bounds__(256) void k_gemm(
    const unsigned char* __restrict__ A, const unsigned char* __restrict__ Bw,
    const float* __restrict__ bias, float* __restrict__ C,
    float* clmin, float* clmax)
{
    const int K = IN_DIM;  // bytes per row (fp8)
    __shared__ __align__(16) unsigned char As[128 * 64];
    __shared__ __align__(16) unsigned char Bs[128 * 64];
    __shared__ float red[8];

    int tid = threadIdx.x;
    int wv = tid >> 6, lane = tid & 63;
    int wr = wv >> 1, wc = wv & 1;           // wave 2x2 position
    int m32 = lane & 31, kh = lane >> 5;     // MFMA lane decomposition
    int bM = blockIdx.y, bN = blockIdx.x;

    // staging: 256 threads x 16B = 4KB per instruction; tile = 8KB -> 2 insts
    int srow = tid >> 2;                     // rows 0..63 for r=0
    int scol = (tid & 3) * 16;
    const unsigned char* gA = A + (size_t)(bM * 128 + srow) * K + scol;
    const unsigned char* gB = Bw + (size_t)(bN * 128 + srow) * K + scol;
    unsigned char* lA = As + tid * 16;       // contiguous: base + lane*16 per wave
    unsigned char* lB = Bs + tid * 16;

    f32x16 acc[2][2] = {};

    for (int k0 = 0; k0 < K; k0 += 64) {
        gload16(gA + k0, lA);
        gload16(gA + k0 + (size_t)64 * K, lA + 64 * 64);
        gload16(gB + k0, lB);
        gload16(gB + k0 + (size_t)64 * K, lB + 64 * 64);
        __syncthreads();

        int8v af[2], bf2[2];
#pragma unroll
        for (int i = 0; i < 2; ++i) {
            af[i]  = *(const int8v*)(As + (wr * 64 + i * 32 + m32) * 64 + kh * 32);
            bf2[i] = *(const int8v*)(Bs + (wc * 64 + i * 32 + m32) * 64 + kh * 32);
        }
#pragma unroll
        for (int mi = 0; mi < 2; ++mi)
#pragma unroll
            for (int ni = 0; ni < 2; ++ni)
                acc[mi][ni] = __builtin_amdgcn_mfma_scale_f32_32x32x64_f8f6f4(
                    af[mi], bf2[ni], acc[mi][ni],
                    0 /*fp8 A*/, 0 /*fp8 B*/, 0, 0x7f, 0, 0x7f);
        __syncthreads();
    }

    // epilogue: bias add, fp32 store, per-cluster min/max
    float bv[2];
#pragma unroll
    for (int ni = 0; ni < 2; ++ni)
        bv[ni] = bias[bN * 128 + wc * 64 + ni * 32 + m32];

    float mn = devinf(), mx = -devinf();
#pragma unroll
    for (int mi = 0; mi < 2; ++mi) {
        int rbase = bM * 128 + wr * 64 + mi * 32 + 4 * kh;
#pragma unroll
        for (int ni = 0; ni < 2; ++ni) {
            int c = bN * 128 + wc * 64 + ni * 32 + m32;
#pragma unroll
            for (int reg = 0; reg < 16; ++reg) {
                int row = rbase + (reg & 3) + 8 * (reg >> 2);  // C/D: 32x32 mapping
                float v = acc[mi][ni][reg] + bv[ni];
                C[(size_t)row * OUT_DIM + c] = v;
                mn = fminf(mn, v);
                mx = fmaxf(mx, v);
            }
        }
    }
    for (int o = 32; o; o >>= 1) {
        mn = fminf(mn, __shfl_down(mn, o));
        mx = fmaxf(mx, __shfl_down(mx, o));
    }
    if (lane == 0) { red[wv] = mn; red[4 + wv] = mx; }
    __syncthreads();
    if (tid == 0) {
        for (int i = 1; i < 4; ++i) { mn = fminf(mn, red[i]); mx = fmaxf(mx, red[4 + i]); }
        int cl = bM >> 3;  // 8 row-blocks of 128 per 1024-row cluster
        atomicMinF(&clmin[cl], mn);
        atomicMaxF(&clmax[cl], mx);
    }
}

// EMA range update + qparams; writes new_range to out tail
__global__ void k_range(const float* st, const float* __restrict__ act_range,
                        const int* __restrict__ ci, float* out_tail, float* qp) {
    int t = threadIdx.x;
    if (t < K_CL) {
        out_tail[2 * t]     = act_range[2 * t];
        out_tail[2 * t + 1] = act_range[2 * t + 1];
    }
    __syncthreads();
    if (t < K_CL) {
        int c = ci[2 * t];
        float omn = act_range[2 * c], omx = act_range[2 * c + 1];
        float nm = omn * 0.999f + st[2 + t] * 0.001f;
        float nx = omx * 0.999f + st[12 + t] * 0.001f;
        out_tail[2 * c]     = nm;
        out_tail[2 * c + 1] = nx;
        float s = (nx - nm) / QMAXF;
        float z = -rintf(nm / s);
        qp[t] = s;
        qp[K_CL + t] = z;
    }
}

// in-place per-cluster fake-quantize of the output
__global__ void k_qout(float4* __restrict__ out, const float* __restrict__ qp, int n4) {
    for (int i = blockIdx.x * blockDim.x + threadIdx.x; i < n4;
         i += gridDim.x * blockDim.x) {
        int cl = i >> 20;  // 1024*4096/4 = 2^20 float4 per cluster
        float s = qp[cl], z = qp[K_CL + cl];
        float4 v = out[i];
        v.x = (fminf(fmaxf(rintf(v.x / s + z), 0.f), QMAXF) - z) * s;
        v.y = (fminf(fmaxf(rintf(v.y / s + z), 0.f), QMAXF) - z) * s;
        v.z = (fminf(fmaxf(rintf(v.z / s + z), 0.f), QMAXF) - z) * s;
        v.w = (fminf(fmaxf(rintf(v.w / s + z), 0.f), QMAXF) - z) * s;
        out[i] = v;
    }
}

extern "C" void kernel_launch(void* const* d_in, const int* in_sizes, int n_in,
                              void* d_out, int out_size, void* d_ws, size_t ws_size,
                              hipStream_t stream) {
    const float* x         = (const float*)d_in[0];
    const float* w         = (const float*)d_in[1];
    const float* bias      = (const float*)d_in[2];
    const float* act_range = (const float*)d_in[3];
    const int*   ci        = (const int*)d_in[4];
    float* out = (float*)d_out;

    float* st = (float*)d_ws;
    unsigned char* x_f8 = (unsigned char*)d_ws + 256;
    unsigned char* w_f8 = x_f8 + (size_t)B_ROWS * IN_DIM;

    k_init<<<1, 64, 0, stream>>>(st);
    k_wminmax<<<2048, 256, 0, stream>>>((const float4*)w, OUT_DIM * IN_DIM / 4, st);
    k_wquant<<<2048, 256, 0, stream>>>((const float4*)w, (uint4*)w_f8,
                                       OUT_DIM * IN_DIM / 16, st);
    k_xcast<<<2048, 256, 0, stream>>>((const float4*)x, (uint4*)x_f8,
                                      B_ROWS * IN_DIM / 16);
    dim3 grid(OUT_DIM / 128, B_ROWS / 128);
    k_gemm<<<grid, 256, 0, stream>>>(x_f8, w_f8, bias, out, st + 2, st + 12);
    k_range<<<1, 64, 0, stream>>>(st, act_range, ci,
                                  out + (size_t)B_ROWS * OUT_DIM, st + 22);
    k_qout<<<2048, 256, 0, stream>>>((float4*)out, st + 22, B_ROWS * OUT_DIM / 4);
}